// Round 1
// baseline (1638.113 us; speedup 1.0000x reference)
//
#include <hip/hip_runtime.h>

#define RNN_T 2048
#define RNN_B 64
#define RNN_H 256

// ---------------------------------------------------------------------------
// Kernel 1: xproj[b,t,:] = embed[x[b,t]] @ Wx + b_fc   (written into hs region)
// Grid: 2048 WGs x 256 threads; each WG does 64 rows x 256 cols, K=256.
// A (gathered embed rows) staged in LDS; Wx streamed from L2 (shared by all WGs).
// Thread micro-tile: 8 rows x 8 cols (cols tj*4 and 128+tj*4 for coalescing).
// ---------------------------------------------------------------------------
__global__ __launch_bounds__(256)
void xproj_kernel(const int* __restrict__ x, const float* __restrict__ embed,
                  const float* __restrict__ Wfc, const float* __restrict__ bfc,
                  float* __restrict__ hsb) {
    __shared__ int ixs[64];
    __shared__ __align__(16) float A[64][260];   // pad 260 to spread staging-write banks
    const int tid = threadIdx.x;
    const long rb0 = (long)blockIdx.x * 64;

    if (tid < 64) ixs[tid] = x[rb0 + tid];
    __syncthreads();

    {   // stage 64 gathered embed rows: 4 threads per row, 16 float4 each
        const int r = tid >> 2, q = tid & 3;
        const float* erow = embed + (long)ixs[r] * RNN_H;
        #pragma unroll
        for (int i = 0; i < 16; ++i) {
            const int c = q * 64 + i * 4;
            *(float4*)&A[r][c] = *(const float4*)(erow + c);
        }
    }
    __syncthreads();

    const int tj = tid & 31, tr = tid >> 5;
    const int r0 = tr * 8, j0 = tj * 4, j1 = 128 + tj * 4;

    float acc[8][8];
    #pragma unroll
    for (int i = 0; i < 8; ++i)
        #pragma unroll
        for (int c = 0; c < 8; ++c) acc[i][c] = 0.f;

    for (int k4 = 0; k4 < 64; ++k4) {
        float4 a[8];
        #pragma unroll
        for (int i = 0; i < 8; ++i) a[i] = *(const float4*)&A[r0 + i][k4 * 4];
        #pragma unroll
        for (int kk = 0; kk < 4; ++kk) {
            const int k = k4 * 4 + kk;
            const float4 wa = *(const float4*)(Wfc + (long)k * RNN_H + j0);
            const float4 wb = *(const float4*)(Wfc + (long)k * RNN_H + j1);
            #pragma unroll
            for (int i = 0; i < 8; ++i) {
                const float av = reinterpret_cast<const float*>(&a[i])[kk];
                acc[i][0] = fmaf(av, wa.x, acc[i][0]);
                acc[i][1] = fmaf(av, wa.y, acc[i][1]);
                acc[i][2] = fmaf(av, wa.z, acc[i][2]);
                acc[i][3] = fmaf(av, wa.w, acc[i][3]);
                acc[i][4] = fmaf(av, wb.x, acc[i][4]);
                acc[i][5] = fmaf(av, wb.y, acc[i][5]);
                acc[i][6] = fmaf(av, wb.z, acc[i][6]);
                acc[i][7] = fmaf(av, wb.w, acc[i][7]);
            }
        }
    }

    const float4 ba = *(const float4*)(bfc + j0);
    const float4 bb = *(const float4*)(bfc + j1);
    #pragma unroll
    for (int i = 0; i < 8; ++i) {
        const long row = rb0 + r0 + i;
        float4 o1 = make_float4(acc[i][0] + ba.x, acc[i][1] + ba.y,
                                acc[i][2] + ba.z, acc[i][3] + ba.w);
        float4 o2 = make_float4(acc[i][4] + bb.x, acc[i][5] + bb.y,
                                acc[i][6] + bb.z, acc[i][7] + bb.w);
        *(float4*)(hsb + row * RNN_H + j0) = o1;
        *(float4*)(hsb + row * RNN_H + j1) = o2;
    }
}

// ---------------------------------------------------------------------------
// Kernel 2: persistent RNN scan. One WG per batch row (64 WGs x 512 threads).
// Wh (256KB) held in VGPRs across the WG: thread (jj, ks) owns
// Wh[ks*64..+64][jj] and Wh[..][jj+128]  -> 128 VGPRs.
// h lives in LDS (broadcast reads); per-step: 128 fmac/thread, 2 barriers.
// Overwrites xproj in-place with hs. Epilogue: out = h_last @ W_out + b_out.
// ---------------------------------------------------------------------------
__global__ __launch_bounds__(512, 2)
void rnn_scan_kernel(const float* __restrict__ Wfc, const float* __restrict__ Wout,
                     const float* __restrict__ bout, float* __restrict__ out,
                     float* __restrict__ hsb) {
    __shared__ __align__(16) float h[RNN_H];
    __shared__ float part[4 * RNN_H];
    const int tid = threadIdx.x;
    const int b = blockIdx.x;
    const int jj = tid & 127, ks = tid >> 7;   // ks in [0,4)

    // load Wh slice into registers (coalesced: consecutive jj lanes)
    const float* Wh = Wfc + RNN_H * RNN_H;     // W_fc rows [256:512]
    float w0[64], w1[64];
    #pragma unroll
    for (int i = 0; i < 64; ++i) {
        w0[i] = Wh[(long)(ks * 64 + i) * RNN_H + jj];
        w1[i] = Wh[(long)(ks * 64 + i) * RNN_H + jj + 128];
    }

    if (tid < RNN_H) h[tid] = 0.f;

    float* xpb = hsb + (long)b * RNN_T * RNN_H;
    float xr = 0.f, xrn = 0.f;
    if (tid < RNN_H) xr = xpb[tid];            // xproj at t=0
    __syncthreads();

    const float4* h4 = (const float4*)h;
    for (int t = 0; t < RNN_T; ++t) {
        // prefetch next step's xproj while we compute (hidden latency)
        if (tid < RNN_H && t + 1 < RNN_T) xrn = xpb[(long)(t + 1) * RNN_H + tid];

        float acc0 = 0.f, acc1 = 0.f;
        #pragma unroll
        for (int i4 = 0; i4 < 16; ++i4) {
            const float4 hv = h4[ks * 16 + i4];   // wave-uniform addr -> broadcast
            acc0 = fmaf(hv.x, w0[i4 * 4 + 0], acc0);
            acc0 = fmaf(hv.y, w0[i4 * 4 + 1], acc0);
            acc0 = fmaf(hv.z, w0[i4 * 4 + 2], acc0);
            acc0 = fmaf(hv.w, w0[i4 * 4 + 3], acc0);
            acc1 = fmaf(hv.x, w1[i4 * 4 + 0], acc1);
            acc1 = fmaf(hv.y, w1[i4 * 4 + 1], acc1);
            acc1 = fmaf(hv.z, w1[i4 * 4 + 2], acc1);
            acc1 = fmaf(hv.w, w1[i4 * 4 + 3], acc1);
        }
        part[ks * RNN_H + jj]       = acc0;
        part[ks * RNN_H + jj + 128] = acc1;
        __syncthreads();

        if (tid < RNN_H) {
            const float s = part[tid] + part[RNN_H + tid] + part[2 * RNN_H + tid]
                          + part[3 * RNN_H + tid] + xr;
            const float e = __expf(2.f * s);
            const float hn = 1.f - 2.f / (e + 1.f);   // tanh(s), saturates correctly
            h[tid] = hn;
            xpb[(long)t * RNN_H + tid] = hn;          // hs output (overwrites xproj)
            xr = xrn;
        }
        __syncthreads();
    }

    // epilogue: out[b,:] = h_last @ W_out + b_out  (h_last is in LDS)
    if (tid < RNN_H) {
        float a0 = 0.f, a1 = 0.f, a2 = 0.f, a3 = 0.f;
        for (int k = 0; k < RNN_H; k += 4) {
            a0 = fmaf(h[k + 0], Wout[(long)(k + 0) * RNN_H + tid], a0);
            a1 = fmaf(h[k + 1], Wout[(long)(k + 1) * RNN_H + tid], a1);
            a2 = fmaf(h[k + 2], Wout[(long)(k + 2) * RNN_H + tid], a2);
            a3 = fmaf(h[k + 3], Wout[(long)(k + 3) * RNN_H + tid], a3);
        }
        out[(long)b * RNN_H + tid] = a0 + a1 + a2 + a3 + bout[tid];
    }
}

extern "C" void kernel_launch(void* const* d_in, const int* in_sizes, int n_in,
                              void* d_out, int out_size, void* d_ws, size_t ws_size,
                              hipStream_t stream) {
    const int*   x     = (const int*)d_in[0];
    const float* embed = (const float*)d_in[1];
    const float* Wfc   = (const float*)d_in[2];
    const float* bfc   = (const float*)d_in[3];
    const float* Wout  = (const float*)d_in[4];
    const float* bout  = (const float*)d_in[5];

    float* out = (float*)d_out;                 // [B, 256]
    float* hsb = out + RNN_B * RNN_H;           // [B, T, H] region

    // Phase 1: xproj -> hs region (in-place consumed by scan)
    xproj_kernel<<<(RNN_B * RNN_T) / 64, 256, 0, stream>>>(x, embed, Wfc, bfc, hsb);
    // Phase 2+3: sequential scan (one WG per batch row) + final projection
    rnn_scan_kernel<<<RNN_B, 512, 0, stream>>>(Wfc, Wout, bout, out, hsb);
}